// Round 6
// baseline (21.754 us; speedup 1.0000x reference)
//
#include <hip/hip_runtime.h>

// Gather per-pixel superpixel logits:
//   out[i, y, x, :] = logits[(i * N_SP + segments[i,y,x]) * WAY + :]
//
// R5 -> R6: single-round kernel is two serialized phases (stage 18 KB ->
// barrier -> store 40 KB); the 16.8 MB seg read never overlaps the 84 MB
// write stream. Fix: demand-load seg INSIDE the store loop. In output-f4
// space thread gl needs pixels p=4gl/5 and p+1; consecutive lanes differ by
// 0-1 pixels so the wave's seg load spans ~4-5 cache lines (coalesced,
// L1-reused). Only the 10 KB logits table (L2-resident) stays behind the
// barrier. Gathers remain in LDS (R2: global random gathers serialize in TA).

constexpr int N_IMG          = 16;
constexpr int SIZE           = 512;
constexpr int N_SP           = 512;
constexpr int WAY            = 5;
constexpr int PIX_PER_IMG    = SIZE * SIZE;                  // 262144
constexpr int NPIX           = N_IMG * PIX_PER_IMG;          // 4194304
constexpr int BLOCK          = 256;
constexpr int PIX_PER_BLOCK  = 2048;
constexpr int BLOCKS_PER_IMG = PIX_PER_IMG / PIX_PER_BLOCK;  // 128
constexpr int TABLE_FLOATS   = N_SP * WAY;                   // 2560 (10 KB)
constexpr int F4_PER_BLOCK   = PIX_PER_BLOCK * WAY / 4;      // 2560
constexpr int F4_PER_THR     = F4_PER_BLOCK / BLOCK;         // 10

__global__ __launch_bounds__(BLOCK) void gather5_stream_kernel(
    const float* __restrict__ logits,
    const int*   __restrict__ seg,
    float*       __restrict__ out)
{
    __shared__ float tab[TABLE_FLOATS];        // 10 KB per-image logits table

    const int img = blockIdx.x >> 7;           // blockIdx.x / BLOCKS_PER_IMG

    // Stage ONLY the logits table (L2-resident: 128 blocks share each image).
    {
        const float2* __restrict__ tsrc =
            reinterpret_cast<const float2*>(logits + img * TABLE_FLOATS);
        float2* dst = reinterpret_cast<float2*>(tab);
        #pragma unroll
        for (int i = 0; i < TABLE_FLOATS / 2 / BLOCK; ++i)
            dst[i * BLOCK + threadIdx.x] = tsrc[i * BLOCK + threadIdx.x];
    }
    __syncthreads();

    const int pixBase = blockIdx.x * PIX_PER_BLOCK;
    const int* __restrict__ segp = seg + pixBase;
    const int plim = (NPIX - 1) - pixBase;     // clamp for p+1 on last block
    float4* __restrict__ o =
        reinterpret_cast<float4*>(out) + (long long)blockIdx.x * F4_PER_BLOCK;

    #pragma unroll
    for (int q = 0; q < F4_PER_THR; ++q) {
        const unsigned gl  = q * BLOCK + threadIdx.x;   // block-local f4 idx
        const unsigned f   = 4u * gl;                   // block-local float idx
        const unsigned p   = f / 5u;                    // local pixel (magic-mul)
        const unsigned off = f - 5u * p;                // 0..4

        // Demand-load seg: wave spans ~205 B -> ~4 lines, L1-reused.
        const int sa = segp[p];
        const int sb = segp[min((int)p + 1, plim)];
        const int r0 = sa * WAY;                        // row base, pixel p
        const int r1 = sb * WAY - 5;                    // row base, pixel p+1

        float4 x;
        float* xf = reinterpret_cast<float*>(&x);
        #pragma unroll
        for (int k = 0; k < 4; ++k) {
            const unsigned w = off + k;                 // 0..7
            const int idx = (w >= 5u ? r1 : r0) + (int)w;
            xf[k] = tab[idx];                           // ds_read_b32
        }
        o[gl] = x;                                      // coalesced 64x16B store
    }
}

extern "C" void kernel_launch(void* const* d_in, const int* in_sizes, int n_in,
                              void* d_out, int out_size, void* d_ws, size_t ws_size,
                              hipStream_t stream) {
    const float* logits = (const float*)d_in[0];
    const int*   seg    = (const int*)d_in[1];
    float*       out    = (float*)d_out;

    const int grid = N_IMG * BLOCKS_PER_IMG;   // 2048 blocks = 8/CU, one round
    gather5_stream_kernel<<<grid, BLOCK, 0, stream>>>(logits, seg, out);
}

// Round 7
// 20.562 us; speedup vs baseline: 1.0580x; 1.0580x over previous
//
#include <hip/hip_runtime.h>

// Gather per-pixel superpixel logits:
//   out[i, y, x, :] = logits[(i * N_SP + segments[i,y,x]) * WAY + :]
//
// R6 -> R7: demand-loading seg regressed (21.8 vs 20.9 staged) -- keep seg
// loads wide+few. Attack the stage/store phase serialization with an async
// 2-tile pipeline instead (T3/T14): stage seg via global_load_lds (no VGPR
// round trip); issue tile1's seg load BEFORE tile0's compute+stores so its
// HBM read hides under the store stream. Exposed seg read halves.

constexpr int N_IMG          = 16;
constexpr int SIZE           = 512;
constexpr int N_SP           = 512;
constexpr int WAY            = 5;
constexpr int PIX_PER_IMG    = SIZE * SIZE;                  // 262144
constexpr int NPIX           = N_IMG * PIX_PER_IMG;          // 4194304
constexpr int BLOCK          = 256;
constexpr int TILE_PX        = 1024;
constexpr int T_TILES        = 2;
constexpr int PIX_PER_BLOCK  = TILE_PX * T_TILES;            // 2048
constexpr int BLOCKS_PER_IMG = PIX_PER_IMG / PIX_PER_BLOCK;  // 128
constexpr int TABLE_FLOATS   = N_SP * WAY;                   // 2560 (10 KB)
constexpr int F4_PER_TILE    = TILE_PX * WAY / 4;            // 1280
constexpr int F4_PER_THR     = F4_PER_TILE / BLOCK;          // 5

// Direct global->LDS DMA, 16 B/lane. LDS dest must be wave-uniform base;
// HW writes lane i at base + i*16 (linear), global src is per-lane.
__device__ __forceinline__ void gld_lds16(const void* g, void* l) {
    __builtin_amdgcn_global_load_lds(
        (const __attribute__((address_space(1))) void*)g,
        (__attribute__((address_space(3))) void*)l, 16, 0, 0);
}

__global__ __launch_bounds__(BLOCK) void gather5_pipe_kernel(
    const float* __restrict__ logits,
    const int*   __restrict__ seg,
    float*       __restrict__ out)
{
    __shared__ float tab[TABLE_FLOATS];          // 10 KB per-image logits
    __shared__ int   segl[T_TILES][TILE_PX + 4]; // 2 x 4 KB seg tiles (+pad)

    const int tid = threadIdx.x;
    const int wid = tid >> 6;                    // wave id 0..3
    const int img = blockIdx.x >> 7;             // / BLOCKS_PER_IMG
    const int pixBase = blockIdx.x * PIX_PER_BLOCK;

    // ---- prologue: async-stage seg tile0 + logits table ----
    // seg tile0: 1024 ints; lane covers ints [4*tid, 4*tid+4).
    gld_lds16(seg + pixBase + 4 * tid, &segl[0][wid * 256]);
    // tab: 2560 floats = 2.5 rounds of 256 lanes x 4 floats.
    const float* tsrc = logits + img * TABLE_FLOATS;
    gld_lds16(tsrc + 4 * tid,        &tab[wid * 256]);
    gld_lds16(tsrc + 1024 + 4 * tid, &tab[1024 + wid * 256]);
    if (tid < 128)
        gld_lds16(tsrc + 2048 + 4 * tid, &tab[2048 + wid * 256]);
    __syncthreads();                             // vmcnt(0): seg0 + tab ready

    // ---- issue tile1's seg load NOW; it lands during tile0's stores ----
    gld_lds16(seg + pixBase + TILE_PX + 4 * tid, &segl[1][wid * 256]);

    float4* __restrict__ ob =
        reinterpret_cast<float4*>(out) + (long long)blockIdx.x * (T_TILES * F4_PER_TILE);

    #pragma unroll
    for (int t = 0; t < T_TILES; ++t) {
        float4* __restrict__ o = ob + t * F4_PER_TILE;
        #pragma unroll
        for (int q = 0; q < F4_PER_THR; ++q) {
            const unsigned gl  = q * BLOCK + tid;   // tile-local f4 idx
            const unsigned f   = 4u * gl;           // tile-local float idx
            const unsigned p   = f / 5u;            // local pixel (magic-mul)
            const unsigned off = f - 5u * p;        // 0..4

            const int sa = segl[t][p];
            const int sb = segl[t][p + 1];          // pad covers p=1023 (unused)
            const int r0 = sa * WAY;
            const int r1 = sb * WAY - 5;

            float4 x;
            float* xf = reinterpret_cast<float*>(&x);
            #pragma unroll
            for (int k = 0; k < 4; ++k) {
                const unsigned w = off + k;         // 0..7
                const int idx = (w >= 5u ? r1 : r0) + (int)w;
                xf[k] = tab[idx];                   // ds_read_b32
            }
            o[gl] = x;                              // coalesced 64x16B store
        }
        if (t + 1 < T_TILES)
            __syncthreads();                        // seg1 landed during tile0
    }
}

extern "C" void kernel_launch(void* const* d_in, const int* in_sizes, int n_in,
                              void* d_out, int out_size, void* d_ws, size_t ws_size,
                              hipStream_t stream) {
    const float* logits = (const float*)d_in[0];
    const int*   seg    = (const int*)d_in[1];
    float*       out    = (float*)d_out;

    const int grid = NPIX / PIX_PER_BLOCK;       // 2048 blocks = 8/CU, one round
    gather5_pipe_kernel<<<grid, BLOCK, 0, stream>>>(logits, seg, out);
}

// Round 9
// 20.560 us; speedup vs baseline: 1.0581x; 1.0001x over previous
//
#include <hip/hip_runtime.h>

// Gather per-pixel superpixel logits:
//   out[i, y, x, :] = logits[(i * N_SP + segments[i,y,x]) * WAY + :]
//
// R8 -> R9: same A/B as R8 (nontemporal stores vs R7), fixing the compile
// error: __builtin_nontemporal_store needs a NATIVE vector type, not
// HIP_vector_type<float,4>. Use ext_vector_type(4) float.
// The 84 MB output stream is 2.6x aggregate L2 (32 MB); default stores
// allocate+evict every line AND evict seg/tab read lines. Output is never
// re-read -> `nt` stores stream past L2. Everything else identical to R7.

constexpr int N_IMG          = 16;
constexpr int SIZE           = 512;
constexpr int N_SP           = 512;
constexpr int WAY            = 5;
constexpr int PIX_PER_IMG    = SIZE * SIZE;                  // 262144
constexpr int NPIX           = N_IMG * PIX_PER_IMG;          // 4194304
constexpr int BLOCK          = 256;
constexpr int TILE_PX        = 1024;
constexpr int T_TILES        = 2;
constexpr int PIX_PER_BLOCK  = TILE_PX * T_TILES;            // 2048
constexpr int BLOCKS_PER_IMG = PIX_PER_IMG / PIX_PER_BLOCK;  // 128
constexpr int TABLE_FLOATS   = N_SP * WAY;                   // 2560 (10 KB)
constexpr int F4_PER_TILE    = TILE_PX * WAY / 4;            // 1280
constexpr int F4_PER_THR     = F4_PER_TILE / BLOCK;          // 5

typedef float f32x4 __attribute__((ext_vector_type(4)));     // native vec4

// Direct global->LDS DMA, 16 B/lane. LDS dest is wave-uniform base;
// HW writes lane i at base + i*16 (linear), global src is per-lane.
__device__ __forceinline__ void gld_lds16(const void* g, void* l) {
    __builtin_amdgcn_global_load_lds(
        (const __attribute__((address_space(1))) void*)g,
        (__attribute__((address_space(3))) void*)l, 16, 0, 0);
}

__global__ __launch_bounds__(BLOCK) void gather5_pipent_kernel(
    const float* __restrict__ logits,
    const int*   __restrict__ seg,
    float*       __restrict__ out)
{
    __shared__ float tab[TABLE_FLOATS];          // 10 KB per-image logits
    __shared__ int   segl[T_TILES][TILE_PX + 4]; // 2 x 4 KB seg tiles (+pad)

    const int tid = threadIdx.x;
    const int wid = tid >> 6;                    // wave id 0..3
    const int img = blockIdx.x >> 7;             // / BLOCKS_PER_IMG
    const int pixBase = blockIdx.x * PIX_PER_BLOCK;

    // ---- prologue: async-stage seg tile0 + logits table ----
    gld_lds16(seg + pixBase + 4 * tid, &segl[0][wid * 256]);
    const float* tsrc = logits + img * TABLE_FLOATS;
    gld_lds16(tsrc + 4 * tid,        &tab[wid * 256]);
    gld_lds16(tsrc + 1024 + 4 * tid, &tab[1024 + wid * 256]);
    if (tid < 128)
        gld_lds16(tsrc + 2048 + 4 * tid, &tab[2048 + wid * 256]);
    __syncthreads();                             // vmcnt(0): seg0 + tab ready

    // ---- issue tile1's seg load NOW; it lands during tile0's stores ----
    gld_lds16(seg + pixBase + TILE_PX + 4 * tid, &segl[1][wid * 256]);

    f32x4* __restrict__ ob =
        reinterpret_cast<f32x4*>(out) + (long long)blockIdx.x * (T_TILES * F4_PER_TILE);

    #pragma unroll
    for (int t = 0; t < T_TILES; ++t) {
        f32x4* __restrict__ o = ob + t * F4_PER_TILE;
        #pragma unroll
        for (int q = 0; q < F4_PER_THR; ++q) {
            const unsigned gl  = q * BLOCK + tid;   // tile-local f4 idx
            const unsigned f   = 4u * gl;           // tile-local float idx
            const unsigned p   = f / 5u;            // local pixel (magic-mul)
            const unsigned off = f - 5u * p;        // 0..4

            const int sa = segl[t][p];
            const int sb = segl[t][p + 1];          // pad covers p=1023 (unused)
            const int r0 = sa * WAY;
            const int r1 = sb * WAY - 5;

            f32x4 x;
            #pragma unroll
            for (int k = 0; k < 4; ++k) {
                const unsigned w = off + k;         // 0..7
                const int idx = (w >= 5u ? r1 : r0) + (int)w;
                x[k] = tab[idx];                    // ds_read_b32
            }
            __builtin_nontemporal_store(x, &o[gl]); // nt: stream past L2
        }
        if (t + 1 < T_TILES)
            __syncthreads();                        // seg1 landed during tile0
    }
}

extern "C" void kernel_launch(void* const* d_in, const int* in_sizes, int n_in,
                              void* d_out, int out_size, void* d_ws, size_t ws_size,
                              hipStream_t stream) {
    const float* logits = (const float*)d_in[0];
    const int*   seg    = (const int*)d_in[1];
    float*       out    = (float*)d_out;

    const int grid = NPIX / PIX_PER_BLOCK;       // 2048 blocks = 8/CU, one round
    gather5_pipent_kernel<<<grid, BLOCK, 0, stream>>>(logits, seg, out);
}